// Round 8
// baseline (3006.036 us; speedup 1.0000x reference)
//
#include <hip/hip_runtime.h>
#include <math.h>

#define Bb 16
#define Nn 2048
#define Dd 256
#define Cc 128
#define Kk 20
#define BIG_NEG -1.0e9f
#define LOG2E 1.4426950408889634f
#define LN2   0.6931471805599453f

// workspace layout (float offsets)
#define WS_EMIS   0
#define WS_MSC    (WS_EMIS + Bb*Nn*Cc)          // means * inv_var, bf16  [C][D]
#define WS_XQ     (WS_MSC + Cc*Dd)              // sum f^2*inv_var  [B*N]
#define WS_ECHAN  (WS_XQ + Bb*Nn)               // const - 0.5*mq   [C]
#define WS_T      (WS_ECHAN + Cc)               // exp(trans_lp)    [C][C]
#define WS_LEN    (WS_T + Cc*Cc)                // len_lp * LOG2E   [K][C]
#define WS_INIT   (WS_LEN + Kk*Cc)              // init_lp * LOG2E  [C]
#define WS_IVAR   (WS_INIT + Cc)                // 1/cov            [D]

typedef __attribute__((ext_vector_type(8))) short short8;
typedef __attribute__((ext_vector_type(4))) float float4v;
typedef __attribute__((ext_vector_type(8))) int int8v;

__device__ __forceinline__ unsigned short f32_to_bf16(float x) {
  unsigned int u = __builtin_bit_cast(unsigned int, x);
  u = (u + 0x7FFFu + ((u >> 16) & 1u)) >> 16;
  return (unsigned short)u;
}

#define DPP_STEP(x, op, ctrl, rmask)                                          \
  do {                                                                        \
    int _yi = __builtin_amdgcn_update_dpp(                                    \
        __builtin_bit_cast(int, x), __builtin_bit_cast(int, x), ctrl, rmask,  \
        0xF, true);                                                           \
    x = op(x, __builtin_bit_cast(float, _yi));                                \
  } while (0)

__device__ __forceinline__ float dpp_add(float a, float b) { return a + b; }

__device__ __forceinline__ float wave_max64(float x) {
  DPP_STEP(x, fmaxf, 0xB1, 0xF);
  DPP_STEP(x, fmaxf, 0x4E, 0xF);
  DPP_STEP(x, fmaxf, 0x141, 0xF);
  DPP_STEP(x, fmaxf, 0x140, 0xF);
  DPP_STEP(x, fmaxf, 0x142, 0xA);
  DPP_STEP(x, fmaxf, 0x143, 0xC);
  return __builtin_bit_cast(float,
      __builtin_amdgcn_readlane(__builtin_bit_cast(int, x), 63));
}

__device__ __forceinline__ float wave_sum64(float x) {
  DPP_STEP(x, dpp_add, 0xB1, 0xF);
  DPP_STEP(x, dpp_add, 0x4E, 0xF);
  DPP_STEP(x, dpp_add, 0x141, 0xF);
  DPP_STEP(x, dpp_add, 0x140, 0xF);
  DPP_STEP(x, dpp_add, 0x142, 0xA);
  DPP_STEP(x, dpp_add, 0x143, 0xC);
  return __builtin_bit_cast(float,
      __builtin_amdgcn_readlane(__builtin_bit_cast(int, x), 63));
}

// interleaved k-permutation: k-pos 2j <-> channel j, 2j+1 <-> channel 64+j
__device__ __forceinline__ int chan_of_k(int kpos) {
  return (kpos & 1) ? (64 + (kpos >> 1)) : (kpos >> 1);
}

// ---------------- small precompute (1 block, 256 threads) — R5 verbatim ----------------
__global__ void prep_kernel(const float* __restrict__ means,
                            const float* __restrict__ cov,
                            const float* __restrict__ tl,
                            const float* __restrict__ il,
                            const float* __restrict__ plr,
                            float* __restrict__ ws) {
  __shared__ float s_iv[Dd];
  __shared__ float s_red[4];
  __shared__ float s_tlse[Cc];
  __shared__ float s_mq[256];
  int tid = threadIdx.x;

  float cv = cov[tid];
  float iv = 1.0f / cv;
  s_iv[tid] = iv;
  ws[WS_IVAR + tid] = iv;
  float lg = __logf(cv);
  #pragma unroll
  for (int off = 1; off < 64; off <<= 1) lg += __shfl_xor(lg, off, 64);
  if ((tid & 63) == 0) s_red[tid >> 6] = lg;
  __syncthreads();
  float logdet = s_red[0] + s_red[1] + s_red[2] + s_red[3];
  float cconst = -0.5f * ((float)Dd * 1.8378770664093453f + logdet);

  // msc in bf16 (B-frag operand for emission MFMA)
  unsigned short* mscb = (unsigned short*)(ws + WS_MSC);
  for (int idx = tid; idx < Cc * Dd; idx += 256) {
    int d = idx & (Dd - 1);
    mscb[idx] = f32_to_bf16(means[idx] * s_iv[d]);
  }
  // echan partials: 2 threads per channel, float4
  {
    int c = tid >> 1, half = tid & 1;
    float acc = 0.0f;
    const float* mrow = means + (size_t)c * Dd + half * 128;
    const float* ivp = s_iv + half * 128;
    #pragma unroll
    for (int d = 0; d < 128; d += 4) {
      float4 mv = *(const float4*)&mrow[d];
      float4 vv = *(const float4*)&ivp[d];
      acc = fmaf(mv.x * mv.x, vv.x, acc);
      acc = fmaf(mv.y * mv.y, vv.y, acc);
      acc = fmaf(mv.z * mv.z, vv.z, acc);
      acc = fmaf(mv.w * mv.w, vv.w, acc);
    }
    s_mq[tid] = acc;
  }
  // Poisson length table in log2 units
  for (int idx = tid; idx < Kk * Cc; idx += 256) {
    int L = idx / Cc + 1;
    int c = idx & (Cc - 1);
    float r = plr[c];
    ws[WS_LEN + idx] = ((float)L * r - __expf(r) - lgammaf((float)(L + 1))) * LOG2E;
  }

  __syncthreads();
  if (tid < Cc)
    ws[WS_ECHAN + tid] = cconst - 0.5f * (s_mq[2 * tid] + s_mq[2 * tid + 1]);

  float x = (tid < Cc) ? il[tid] : -INFINITY;
  float mx = x;
  #pragma unroll
  for (int off = 1; off < 64; off <<= 1) mx = fmaxf(mx, __shfl_xor(mx, off, 64));
  if ((tid & 63) == 0) s_red[tid >> 6] = mx;
  __syncthreads();
  float M = fmaxf(s_red[0], s_red[1]);
  float se = (tid < Cc) ? __expf(x - M) : 0.0f;
  #pragma unroll
  for (int off = 1; off < 64; off <<= 1) se += __shfl_xor(se, off, 64);
  __syncthreads();
  if ((tid & 63) == 0) s_red[tid >> 6] = se;
  __syncthreads();
  float lse = M + __logf(s_red[0] + s_red[1]);
  if (tid < Cc) ws[WS_INIT + tid] = (x - lse) * LOG2E;   // log2 units

  if (tid < Cc) {
    int j = tid;
    float m2 = -INFINITY;
    for (int i = 0; i < Cc; i++) if (i != j) m2 = fmaxf(m2, tl[i * Cc + j]);
    float s2 = 0.0f;
    for (int i = 0; i < Cc; i++) if (i != j) s2 += __expf(tl[i * Cc + j] - m2);
    s_tlse[j] = m2 + __logf(s2);
  }
  __syncthreads();
  for (int idx = tid; idx < Cc * Cc; idx += 256) {
    int i = idx / Cc;
    int j = idx & (Cc - 1);
    ws[WS_T + idx] = (i == j) ? 0.0f : __expf(tl[idx] - s_tlse[j]);
  }
}

// ---------------- xq[b,n] = sum_d f^2 * inv_var — R5 verbatim ----------------
__global__ void xq_kernel(const float* __restrict__ f, float* __restrict__ ws) {
  int pos = blockIdx.x * 4 + (threadIdx.x >> 6);
  int lane = threadIdx.x & 63;
  const float4 fv = *(const float4*)&f[(size_t)pos * Dd + lane * 4];
  const float4 vv = *(const float4*)&ws[WS_IVAR + lane * 4];
  float a = fv.x * fv.x * vv.x + fv.y * fv.y * vv.y +
            fv.z * fv.z * vv.z + fv.w * fv.w * vv.w;
  #pragma unroll
  for (int off = 1; off < 64; off <<= 1) a += __shfl_xor(a, off, 64);
  if (lane == 0) ws[WS_XQ + pos] = a;
}

// ------------ emission via MFMA: 32n x 128c per block, 4 waves — R5 verbatim ------------
__launch_bounds__(256)
__global__ void emis_mfma_kernel(const float* __restrict__ f, float* __restrict__ ws) {
  const unsigned short* msc = (const unsigned short*)(ws + WS_MSC);
  float* emis = ws + WS_EMIS;
  int tid = threadIdx.x;
  int w = tid >> 6, lane = tid & 63, g = lane >> 4, l16 = lane & 15;
  int b = blockIdx.x >> 6;
  int n0 = (blockIdx.x & 63) << 5;
  int c0 = w << 5;

  const float* fbase = f + (size_t)(b * Nn + n0) * Dd;
  float4v acc[2][2];
  #pragma unroll
  for (int rt = 0; rt < 2; rt++)
    #pragma unroll
    for (int ct = 0; ct < 2; ct++) acc[rt][ct] = (float4v){0.f, 0.f, 0.f, 0.f};

  #pragma unroll
  for (int k0 = 0; k0 < Dd; k0 += 32) {
    int kk = k0 + g * 8;
    short8 afr[2], bfr[2];
    #pragma unroll
    for (int rt = 0; rt < 2; rt++) {
      const float* src = fbase + (size_t)(rt * 16 + l16) * Dd + kk;
      float4 v0 = *(const float4*)src;
      float4 v1 = *(const float4*)(src + 4);
      short8 fr;
      fr[0] = (short)f32_to_bf16(v0.x); fr[1] = (short)f32_to_bf16(v0.y);
      fr[2] = (short)f32_to_bf16(v0.z); fr[3] = (short)f32_to_bf16(v0.w);
      fr[4] = (short)f32_to_bf16(v1.x); fr[5] = (short)f32_to_bf16(v1.y);
      fr[6] = (short)f32_to_bf16(v1.z); fr[7] = (short)f32_to_bf16(v1.w);
      afr[rt] = fr;
    }
    #pragma unroll
    for (int ct = 0; ct < 2; ct++)
      bfr[ct] = *(const short8*)&msc[(size_t)(c0 + ct * 16 + l16) * Dd + kk];
    #pragma unroll
    for (int rt = 0; rt < 2; rt++)
      #pragma unroll
      for (int ct = 0; ct < 2; ct++)
        acc[rt][ct] = __builtin_amdgcn_mfma_f32_16x16x32_bf16(afr[rt], bfr[ct], acc[rt][ct], 0, 0, 0);
  }

  #pragma unroll
  for (int rt = 0; rt < 2; rt++) {
    #pragma unroll
    for (int ct = 0; ct < 2; ct++) {
      int cc = c0 + ct * 16 + l16;
      float ec = ws[WS_ECHAN + cc];
      #pragma unroll
      for (int r = 0; r < 4; r++) {
        int row = rt * 16 + g * 4 + r;
        int nn = n0 + row;
        emis[(size_t)(b * Nn + nn) * Cc + cc] =
            (ec - 0.5f * ws[WS_XQ + b * Nn + nn] + acc[rt][ct][r]) * LOG2E;
      }
    }
  }
}

// -------- scan: ONE WAVE per block handles TWO batches (b, b+8); R5 numerics --------
__launch_bounds__(64, 1)
__global__ void scan_kernel(const int* __restrict__ lengths,
                            const float* __restrict__ ws,
                            float* __restrict__ out) {
  __shared__ unsigned short s_p[2][64];   // per-batch fp8 p-values, pair-interleaved
  int lane = threadIdx.x;
  int lg4 = lane >> 4, n16 = lane & 15;
  int bA = blockIdx.x, bB = blockIdx.x + 8;
  int lenA = lengths[bA], lenB = lengths[bB];
  int tmax = max(lenA, lenB);
  const float* emisP[2];
  emisP[0] = ws + WS_EMIS + (size_t)bA * Nn * Cc;
  emisP[1] = ws + WS_EMIS + (size_t)bB * Nn * Cc;
  int lenP[2] = {lenA, lenB};
  int outP[2] = {bA, bB};
  const int sc1 = 0x7F7F7F7F;             // E8M0 scale = 1.0

  // ---- shared T fp8 B-frags (R5 verbatim) ----
  int8v Tf[8];
  {
    const float* T = ws + WS_T;
    #pragma unroll
    for (int nt = 0; nt < 8; nt++) {
      const float* Trow = &T[(size_t)(nt * 16 + n16) * Cc];
      #pragma unroll
      for (int dw = 0; dw < 8; dw++) {
        int kbase = lg4 * 32 + dw * 4;
        float t0 = 64.0f * Trow[chan_of_k(kbase + 0)];
        float t1 = 64.0f * Trow[chan_of_k(kbase + 1)];
        float t2 = 64.0f * Trow[chan_of_k(kbase + 2)];
        float t3 = 64.0f * Trow[chan_of_k(kbase + 3)];
        int d = __builtin_amdgcn_cvt_pk_fp8_f32(t0, t1, 0, false);
        d = __builtin_amdgcn_cvt_pk_fp8_f32(t2, t3, d, true);
        Tf[nt][dw] = d;
      }
    }
  }

  // ---- shared per-channel constants (R5 verbatim) ----
  int cidx[2] = {lane, lane + 64};
  float len0[2], E2[2][Kk - 1];
  #pragma unroll
  for (int ch = 0; ch < 2; ch++) {
    float lenv[Kk];
    #pragma unroll
    for (int k = 0; k < Kk; k++) lenv[k] = ws[WS_LEN + k * Cc + cidx[ch]];
    len0[ch] = lenv[0];
    #pragma unroll
    for (int k = 0; k < Kk - 1; k++)
      E2[ch][k] = __builtin_amdgcn_exp2f(lenv[k + 1] - lenv[k]);
  }

  // ---- per-batch state (R5 verbatim, duplicated) ----
  float wv[2][2][Kk - 1];
  float aa[2][2], L19[2][2], gnew[2][2], cum[2][2];
  float e[2][2][8], en[2][2][8];
  #pragma unroll
  for (int bi = 0; bi < 2; bi++) {
    #pragma unroll
    for (int ch = 0; ch < 2; ch++) {
      #pragma unroll
      for (int j = 0; j < Kk - 1; j++) wv[bi][ch][j] = 0.0f;
      aa[bi][ch] = 0.0f;
      L19[bi][ch] = -1.0e30f;
      gnew[bi][ch] = ws[WS_INIT + cidx[ch]];
      cum[bi][ch] = emisP[bi][0 * Cc + cidx[ch]];
      #pragma unroll
      for (int i = 0; i < 8; i++)
        e[bi][ch][i] = emisP[bi][(size_t)(1 + i) * Cc + cidx[ch]];
    }
  }

  bool done = false;
  for (int tg = 1; tg <= Nn && !done; tg += 8) {
    #pragma unroll
    for (int i = 0; i < 8; i++) {
      int t = tg + i;
      #pragma unroll
      for (int bi = 0; bi < 2; bi++) {
        // prefetch next group's row (no barriers -> loads stay outstanding)
        {
          int r = tg + 8 + i; if (r > Nn - 1) r = Nn - 1;
          en[bi][0][i] = emisP[bi][(size_t)r * Cc + lane];
          en[bi][1][i] = emisP[bi][(size_t)r * Cc + lane + 64];
        }

        // ---- Phase A (R5 verbatim): short fixup chain ----
        float h0[2], mm[2], eh[2], sfix[2], mab[2];
        #pragma unroll
        for (int ch = 0; ch < 2; ch++) {
          h0[ch] = gnew[bi][ch] + len0[ch];
          mm[ch] = fmaxf(L19[bi][ch], h0[ch]);
          float eL = __builtin_amdgcn_exp2f(L19[bi][ch] - mm[ch]);
          eh[ch] = __builtin_amdgcn_exp2f(h0[ch] - mm[ch]);
          sfix[ch] = eL + eh[ch];
          mab[ch] = mm[ch] + cum[bi][ch];
        }
        float lmax = fmaxf(mab[0], mab[1]);
        float wm = wave_max64(lmax);
        float p0 = sfix[0] * __builtin_amdgcn_exp2f(mab[0] - wm);
        float p1 = sfix[1] * __builtin_amdgcn_exp2f(mab[1] - wm);
        int pk = __builtin_amdgcn_cvt_pk_fp8_f32(p0, p1, 0, false);
        s_p[bi][lane] = (unsigned short)pk;
        bool is_out = (t == lenP[bi]);
        if (is_out) {
          float psum = wave_sum64(p0 + p1);
          if (lane == 0) out[outP[bi]] = LN2 * (wm + __builtin_amdgcn_logf(psum));
        }

        // A-frag: 32 fp8 k-bytes (same-wave LDS, hardware-ordered, no barrier)
        const int4* ap = (const int4*)((const char*)s_p[bi] + lg4 * 32);
        int4 ra = ap[0];
        int4 rb = ap[1];
        int8v A;
        A[0] = ra.x; A[1] = ra.y; A[2] = ra.z; A[3] = ra.w;
        A[4] = rb.x; A[5] = rb.y; A[6] = rb.z; A[7] = rb.w;

        // ---- shadow window (R5 verbatim + inert phi clamp) ----
        float S19n[2];
        #pragma unroll
        for (int ch = 0; ch < 2; ch++) {
          // clamp: only active when window sum < 2^-100 of its own anchor;
          // removes the lone 0*inf path without changing results otherwise
          float phi = __builtin_amdgcn_exp2f(fminf(aa[bi][ch] - mm[ch], 100.0f));
          #pragma unroll
          for (int j = Kk - 2; j >= 1; j--)
            wv[bi][ch][j] = wv[bi][ch][j - 1] * (E2[ch][j] * phi);
          wv[bi][ch][0] = eh[ch] * E2[ch][0];
          float s4[5];
          s4[0] = (wv[bi][ch][0] + wv[bi][ch][1]) + (wv[bi][ch][2] + wv[bi][ch][3]);
          s4[1] = (wv[bi][ch][4] + wv[bi][ch][5]) + (wv[bi][ch][6] + wv[bi][ch][7]);
          s4[2] = (wv[bi][ch][8] + wv[bi][ch][9]) + (wv[bi][ch][10] + wv[bi][ch][11]);
          s4[3] = (wv[bi][ch][12] + wv[bi][ch][13]) + (wv[bi][ch][14] + wv[bi][ch][15]);
          s4[4] = (wv[bi][ch][16] + wv[bi][ch][17]) + wv[bi][ch][18];
          S19n[ch] = ((s4[0] + s4[1]) + (s4[2] + s4[3])) + s4[4];
        }

        // ---- matvec: q*64 = T64 x p (R5 verbatim) ----
        float4v D0, D1, D2, D3, D4, D5, D6, D7;
        {
          float4v z = {0.0f, 0.0f, 0.0f, 0.0f};
          D0 = __builtin_amdgcn_mfma_scale_f32_16x16x128_f8f6f4(A, Tf[0], z, 0, 0, 0, sc1, 0, sc1);
          D1 = __builtin_amdgcn_mfma_scale_f32_16x16x128_f8f6f4(A, Tf[1], z, 0, 0, 0, sc1, 0, sc1);
          D2 = __builtin_amdgcn_mfma_scale_f32_16x16x128_f8f6f4(A, Tf[2], z, 0, 0, 0, sc1, 0, sc1);
          D3 = __builtin_amdgcn_mfma_scale_f32_16x16x128_f8f6f4(A, Tf[3], z, 0, 0, 0, sc1, 0, sc1);
          D4 = __builtin_amdgcn_mfma_scale_f32_16x16x128_f8f6f4(A, Tf[4], z, 0, 0, 0, sc1, 0, sc1);
          D5 = __builtin_amdgcn_mfma_scale_f32_16x16x128_f8f6f4(A, Tf[5], z, 0, 0, 0, sc1, 0, sc1);
          D6 = __builtin_amdgcn_mfma_scale_f32_16x16x128_f8f6f4(A, Tf[6], z, 0, 0, 0, sc1, 0, sc1);
          D7 = __builtin_amdgcn_mfma_scale_f32_16x16x128_f8f6f4(A, Tf[7], z, 0, 0, 0, sc1, 0, sc1);
        }
        float q0 = (lg4 == 0) ? D0[0] : (lg4 == 1) ? D1[0] : (lg4 == 2) ? D2[0] : D3[0];
        float q1 = (lg4 == 0) ? D4[0] : (lg4 == 1) ? D5[0] : (lg4 == 2) ? D6[0] : D7[0];
        float rel0 = cum[bi][0] - wm;
        float rel1 = cum[bi][1] - wm;
        gnew[bi][0] = (q0 > 0.0f) ? (__builtin_amdgcn_logf(q0) - 6.0f - rel0) : BIG_NEG;
        gnew[bi][1] = (q1 > 0.0f) ? (__builtin_amdgcn_logf(q1) - 6.0f - rel1) : BIG_NEG;

        // ---- commit (R5 verbatim) ----
        #pragma unroll
        for (int ch = 0; ch < 2; ch++) {
          aa[bi][ch] = mm[ch];
          L19[bi][ch] = mm[ch] + __builtin_amdgcn_logf(S19n[ch]);
          cum[bi][ch] += e[bi][ch][i];
        }
      }
      if (t == tmax) { done = true; break; }
    }
    if (!done) {
      #pragma unroll
      for (int i = 0; i < 8; i++) {
        e[0][0][i] = en[0][0][i]; e[0][1][i] = en[0][1][i];
        e[1][0][i] = en[1][0][i]; e[1][1][i] = en[1][1][i];
      }
    }
  }
}

extern "C" void kernel_launch(void* const* d_in, const int* in_sizes, int n_in,
                              void* d_out, int out_size, void* d_ws, size_t ws_size,
                              hipStream_t stream) {
  const float* features = (const float*)d_in[0];
  const int* lengths = (const int*)d_in[1];
  const float* means = (const float*)d_in[2];
  const float* cov = (const float*)d_in[3];
  const float* tl = (const float*)d_in[4];
  const float* il = (const float*)d_in[5];
  const float* plr = (const float*)d_in[6];
  float* out = (float*)d_out;
  float* ws = (float*)d_ws;

  prep_kernel<<<1, 256, 0, stream>>>(means, cov, tl, il, plr, ws);
  xq_kernel<<<(Bb * Nn) / 4, 256, 0, stream>>>(features, ws);
  emis_mfma_kernel<<<Bb * (Nn / 32), 256, 0, stream>>>(features, ws);
  scan_kernel<<<8, 64, 0, stream>>>(lengths, ws, out);
}

// Round 9
// 2863.188 us; speedup vs baseline: 1.0499x; 1.0499x over previous
//
#include <hip/hip_runtime.h>
#include <math.h>

#define Bb 16
#define Nn 2048
#define Dd 256
#define Cc 128
#define Kk 20
#define BIG_NEG -1.0e9f
#define LOG2E 1.4426950408889634f
#define LN2   0.6931471805599453f

// workspace layout (float offsets)
#define WS_EMIS   0
#define WS_MSC    (WS_EMIS + Bb*Nn*Cc)          // means * inv_var, bf16  [C][D]
#define WS_XQ     (WS_MSC + Cc*Dd)              // sum f^2*inv_var  [B*N]
#define WS_ECHAN  (WS_XQ + Bb*Nn)               // const - 0.5*mq   [C]
#define WS_T      (WS_ECHAN + Cc)               // exp(trans_lp)    [C][C]
#define WS_LEN    (WS_T + Cc*Cc)                // len_lp * LOG2E   [K][C]
#define WS_INIT   (WS_LEN + Kk*Cc)              // init_lp * LOG2E  [C]
#define WS_IVAR   (WS_INIT + Cc)                // 1/cov            [D]

typedef __attribute__((ext_vector_type(8))) short short8;
typedef __attribute__((ext_vector_type(4))) float float4v;
typedef __attribute__((ext_vector_type(8))) int int8v;
typedef __attribute__((ext_vector_type(2))) float float2v;

__device__ __forceinline__ unsigned short f32_to_bf16(float x) {
  unsigned int u = __builtin_bit_cast(unsigned int, x);
  u = (u + 0x7FFFu + ((u >> 16) & 1u)) >> 16;
  return (unsigned short)u;
}

#define DPP_STEP(x, op, ctrl, rmask)                                          \
  do {                                                                        \
    int _yi = __builtin_amdgcn_update_dpp(                                    \
        __builtin_bit_cast(int, x), __builtin_bit_cast(int, x), ctrl, rmask,  \
        0xF, true);                                                           \
    x = op(x, __builtin_bit_cast(float, _yi));                                \
  } while (0)

__device__ __forceinline__ float dpp_add(float a, float b) { return a + b; }

__device__ __forceinline__ float wave_max64(float x) {
  DPP_STEP(x, fmaxf, 0xB1, 0xF);
  DPP_STEP(x, fmaxf, 0x4E, 0xF);
  DPP_STEP(x, fmaxf, 0x141, 0xF);
  DPP_STEP(x, fmaxf, 0x140, 0xF);
  DPP_STEP(x, fmaxf, 0x142, 0xA);
  DPP_STEP(x, fmaxf, 0x143, 0xC);
  return __builtin_bit_cast(float,
      __builtin_amdgcn_readlane(__builtin_bit_cast(int, x), 63));
}

__device__ __forceinline__ float wave_sum64(float x) {
  DPP_STEP(x, dpp_add, 0xB1, 0xF);
  DPP_STEP(x, dpp_add, 0x4E, 0xF);
  DPP_STEP(x, dpp_add, 0x141, 0xF);
  DPP_STEP(x, dpp_add, 0x140, 0xF);
  DPP_STEP(x, dpp_add, 0x142, 0xA);
  DPP_STEP(x, dpp_add, 0x143, 0xC);
  return __builtin_bit_cast(float,
      __builtin_amdgcn_readlane(__builtin_bit_cast(int, x), 63));
}

__device__ __forceinline__ float2v v2max(float2v a, float2v b) {
  float2v r; r.x = fmaxf(a.x, b.x); r.y = fmaxf(a.y, b.y); return r;
}
__device__ __forceinline__ float2v v2minc(float2v a, float c) {
  float2v r; r.x = fminf(a.x, c); r.y = fminf(a.y, c); return r;
}
__device__ __forceinline__ float2v v2exp2(float2v a) {
  float2v r; r.x = __builtin_amdgcn_exp2f(a.x); r.y = __builtin_amdgcn_exp2f(a.y); return r;
}
__device__ __forceinline__ float2v v2log2(float2v a) {
  float2v r; r.x = __builtin_amdgcn_logf(a.x); r.y = __builtin_amdgcn_logf(a.y); return r;
}

// interleaved k-permutation: k-pos 2j <-> channel j, 2j+1 <-> channel 64+j
__device__ __forceinline__ int chan_of_k(int kpos) {
  return (kpos & 1) ? (64 + (kpos >> 1)) : (kpos >> 1);
}

// ---------------- small precompute (1 block, 256 threads) ----------------
__global__ void prep_kernel(const float* __restrict__ means,
                            const float* __restrict__ cov,
                            const float* __restrict__ tl,
                            const float* __restrict__ il,
                            const float* __restrict__ plr,
                            float* __restrict__ ws) {
  __shared__ float s_iv[Dd];
  __shared__ float s_red[4];
  __shared__ float s_tlse[Cc];
  __shared__ float s_mq[256];
  int tid = threadIdx.x;

  float cv = cov[tid];
  float iv = 1.0f / cv;
  s_iv[tid] = iv;
  ws[WS_IVAR + tid] = iv;
  float lg = __logf(cv);
  #pragma unroll
  for (int off = 1; off < 64; off <<= 1) lg += __shfl_xor(lg, off, 64);
  if ((tid & 63) == 0) s_red[tid >> 6] = lg;
  __syncthreads();
  float logdet = s_red[0] + s_red[1] + s_red[2] + s_red[3];
  float cconst = -0.5f * ((float)Dd * 1.8378770664093453f + logdet);

  unsigned short* mscb = (unsigned short*)(ws + WS_MSC);
  for (int idx = tid; idx < Cc * Dd; idx += 256) {
    int d = idx & (Dd - 1);
    mscb[idx] = f32_to_bf16(means[idx] * s_iv[d]);
  }
  {
    int c = tid >> 1, half = tid & 1;
    float acc = 0.0f;
    const float* mrow = means + (size_t)c * Dd + half * 128;
    const float* ivp = s_iv + half * 128;
    #pragma unroll
    for (int d = 0; d < 128; d += 4) {
      float4 mv = *(const float4*)&mrow[d];
      float4 vv = *(const float4*)&ivp[d];
      acc = fmaf(mv.x * mv.x, vv.x, acc);
      acc = fmaf(mv.y * mv.y, vv.y, acc);
      acc = fmaf(mv.z * mv.z, vv.z, acc);
      acc = fmaf(mv.w * mv.w, vv.w, acc);
    }
    s_mq[tid] = acc;
  }
  for (int idx = tid; idx < Kk * Cc; idx += 256) {
    int L = idx / Cc + 1;
    int c = idx & (Cc - 1);
    float r = plr[c];
    ws[WS_LEN + idx] = ((float)L * r - __expf(r) - lgammaf((float)(L + 1))) * LOG2E;
  }

  __syncthreads();
  if (tid < Cc)
    ws[WS_ECHAN + tid] = cconst - 0.5f * (s_mq[2 * tid] + s_mq[2 * tid + 1]);

  float x = (tid < Cc) ? il[tid] : -INFINITY;
  float mx = x;
  #pragma unroll
  for (int off = 1; off < 64; off <<= 1) mx = fmaxf(mx, __shfl_xor(mx, off, 64));
  if ((tid & 63) == 0) s_red[tid >> 6] = mx;
  __syncthreads();
  float M = fmaxf(s_red[0], s_red[1]);
  float se = (tid < Cc) ? __expf(x - M) : 0.0f;
  #pragma unroll
  for (int off = 1; off < 64; off <<= 1) se += __shfl_xor(se, off, 64);
  __syncthreads();
  if ((tid & 63) == 0) s_red[tid >> 6] = se;
  __syncthreads();
  float lse = M + __logf(s_red[0] + s_red[1]);
  if (tid < Cc) ws[WS_INIT + tid] = (x - lse) * LOG2E;   // log2 units

  if (tid < Cc) {
    int j = tid;
    float m2 = -INFINITY;
    for (int i = 0; i < Cc; i++) if (i != j) m2 = fmaxf(m2, tl[i * Cc + j]);
    float s2 = 0.0f;
    for (int i = 0; i < Cc; i++) if (i != j) s2 += __expf(tl[i * Cc + j] - m2);
    s_tlse[j] = m2 + __logf(s2);
  }
  __syncthreads();
  for (int idx = tid; idx < Cc * Cc; idx += 256) {
    int i = idx / Cc;
    int j = idx & (Cc - 1);
    ws[WS_T + idx] = (i == j) ? 0.0f : __expf(tl[idx] - s_tlse[j]);
  }
}

// ---------------- xq[b,n] = sum_d f^2 * inv_var (one wave per position) ----------------
__global__ void xq_kernel(const float* __restrict__ f, float* __restrict__ ws) {
  int pos = blockIdx.x * 4 + (threadIdx.x >> 6);
  int lane = threadIdx.x & 63;
  const float4 fv = *(const float4*)&f[(size_t)pos * Dd + lane * 4];
  const float4 vv = *(const float4*)&ws[WS_IVAR + lane * 4];
  float a = fv.x * fv.x * vv.x + fv.y * fv.y * vv.y +
            fv.z * fv.z * vv.z + fv.w * fv.w * vv.w;
  #pragma unroll
  for (int off = 1; off < 64; off <<= 1) a += __shfl_xor(a, off, 64);
  if (lane == 0) ws[WS_XQ + pos] = a;
}

// ------------ emission via MFMA: 32n x 128c per block, 4 waves ------------
__launch_bounds__(256)
__global__ void emis_mfma_kernel(const float* __restrict__ f, float* __restrict__ ws) {
  const unsigned short* msc = (const unsigned short*)(ws + WS_MSC);
  float* emis = ws + WS_EMIS;
  int tid = threadIdx.x;
  int w = tid >> 6, lane = tid & 63, g = lane >> 4, l16 = lane & 15;
  int b = blockIdx.x >> 6;
  int n0 = (blockIdx.x & 63) << 5;
  int c0 = w << 5;

  const float* fbase = f + (size_t)(b * Nn + n0) * Dd;
  float4v acc[2][2];
  #pragma unroll
  for (int rt = 0; rt < 2; rt++)
    #pragma unroll
    for (int ct = 0; ct < 2; ct++) acc[rt][ct] = (float4v){0.f, 0.f, 0.f, 0.f};

  #pragma unroll
  for (int k0 = 0; k0 < Dd; k0 += 32) {
    int kk = k0 + g * 8;
    short8 afr[2], bfr[2];
    #pragma unroll
    for (int rt = 0; rt < 2; rt++) {
      const float* src = fbase + (size_t)(rt * 16 + l16) * Dd + kk;
      float4 v0 = *(const float4*)src;
      float4 v1 = *(const float4*)(src + 4);
      short8 fr;
      fr[0] = (short)f32_to_bf16(v0.x); fr[1] = (short)f32_to_bf16(v0.y);
      fr[2] = (short)f32_to_bf16(v0.z); fr[3] = (short)f32_to_bf16(v0.w);
      fr[4] = (short)f32_to_bf16(v1.x); fr[5] = (short)f32_to_bf16(v1.y);
      fr[6] = (short)f32_to_bf16(v1.z); fr[7] = (short)f32_to_bf16(v1.w);
      afr[rt] = fr;
    }
    #pragma unroll
    for (int ct = 0; ct < 2; ct++)
      bfr[ct] = *(const short8*)&msc[(size_t)(c0 + ct * 16 + l16) * Dd + kk];
    #pragma unroll
    for (int rt = 0; rt < 2; rt++)
      #pragma unroll
      for (int ct = 0; ct < 2; ct++)
        acc[rt][ct] = __builtin_amdgcn_mfma_f32_16x16x32_bf16(afr[rt], bfr[ct], acc[rt][ct], 0, 0, 0);
  }

  #pragma unroll
  for (int rt = 0; rt < 2; rt++) {
    #pragma unroll
    for (int ct = 0; ct < 2; ct++) {
      int cc = c0 + ct * 16 + l16;
      float ec = ws[WS_ECHAN + cc];
      #pragma unroll
      for (int r = 0; r < 4; r++) {
        int row = rt * 16 + g * 4 + r;
        int nn = n0 + row;
        emis[(size_t)(b * Nn + nn) * Cc + cc] =
            (ec - 0.5f * ws[WS_XQ + b * Nn + nn] + acc[rt][ct][r]) * LOG2E;
      }
    }
  }
}

// ---- scan: ONE WAVE per block, TWO batches MANUALLY JAMMED; packed fp32 window ----
__launch_bounds__(64, 1)
__global__ void scan_kernel(const int* __restrict__ lengths,
                            const float* __restrict__ ws,
                            float* __restrict__ out) {
  __shared__ unsigned short s_p[2][64];
  int lane = threadIdx.x;
  int lg4 = lane >> 4, n16 = lane & 15;
  int bA = blockIdx.x, bB = blockIdx.x + 8;
  int lenP[2] = {lengths[bA], lengths[bB]};
  int tmax = max(lenP[0], lenP[1]);
  const float* emis0 = ws + WS_EMIS + (size_t)bA * Nn * Cc;
  const float* emis1 = ws + WS_EMIS + (size_t)bB * Nn * Cc;
  const int sc1 = 0x7F7F7F7F;

  // ---- shared T fp8 B-frags ----
  int8v Tf[8];
  {
    const float* T = ws + WS_T;
    #pragma unroll
    for (int nt = 0; nt < 8; nt++) {
      const float* Trow = &T[(size_t)(nt * 16 + n16) * Cc];
      #pragma unroll
      for (int dw = 0; dw < 8; dw++) {
        int kbase = lg4 * 32 + dw * 4;
        float t0 = 64.0f * Trow[chan_of_k(kbase + 0)];
        float t1 = 64.0f * Trow[chan_of_k(kbase + 1)];
        float t2 = 64.0f * Trow[chan_of_k(kbase + 2)];
        float t3 = 64.0f * Trow[chan_of_k(kbase + 3)];
        int d = __builtin_amdgcn_cvt_pk_fp8_f32(t0, t1, 0, false);
        d = __builtin_amdgcn_cvt_pk_fp8_f32(t2, t3, d, true);
        Tf[nt][dw] = d;
      }
    }
  }

  // ---- shared per-channel constants, packed (x=ch lane, y=ch lane+64) ----
  float2v len0v, E2v[Kk - 1];
  {
    float2v prev;
    prev.x = ws[WS_LEN + 0 * Cc + lane];
    prev.y = ws[WS_LEN + 0 * Cc + lane + 64];
    len0v = prev;
    #pragma unroll
    for (int k = 1; k < Kk; k++) {
      float2v cur;
      cur.x = ws[WS_LEN + k * Cc + lane];
      cur.y = ws[WS_LEN + k * Cc + lane + 64];
      E2v[k - 1] = v2exp2(cur - prev);
      prev = cur;
    }
  }

  // ---- per-batch state (packed channels) ----
  float2v wvv[2][Kk - 1], aav[2], L19v[2], gnewv[2], cumv[2];
  float2v ev[2][8], env[2][8];
  {
    float2v iv; iv.x = ws[WS_INIT + lane]; iv.y = ws[WS_INIT + lane + 64];
    #pragma unroll
    for (int bi = 0; bi < 2; bi++) {
      #pragma unroll
      for (int j = 0; j < Kk - 1; j++) wvv[bi][j] = (float2v){0.0f, 0.0f};
      aav[bi] = (float2v){0.0f, 0.0f};
      L19v[bi] = (float2v){-1.0e30f, -1.0e30f};
      gnewv[bi] = iv;
    }
    cumv[0].x = emis0[lane];      cumv[0].y = emis0[lane + 64];
    cumv[1].x = emis1[lane];      cumv[1].y = emis1[lane + 64];
    #pragma unroll
    for (int i = 0; i < 8; i++) {
      ev[0][i].x = emis0[(size_t)(1 + i) * Cc + lane];
      ev[0][i].y = emis0[(size_t)(1 + i) * Cc + lane + 64];
      ev[1][i].x = emis1[(size_t)(1 + i) * Cc + lane];
      ev[1][i].y = emis1[(size_t)(1 + i) * Cc + lane + 64];
    }
  }

  bool done = false;
  for (int tg = 1; tg <= Nn && !done; tg += 8) {
    #pragma unroll
    for (int i = 0; i < 8; i++) {
      int t = tg + i;
      {
        int r = tg + 8 + i; if (r > Nn - 1) r = Nn - 1;
        env[0][i].x = emis0[(size_t)r * Cc + lane];
        env[0][i].y = emis0[(size_t)r * Cc + lane + 64];
        env[1][i].x = emis1[(size_t)r * Cc + lane];
        env[1][i].y = emis1[(size_t)r * Cc + lane + 64];
      }

      // ---- Phase A, both batches jammed ----
      float2v h0v0 = gnewv[0] + len0v;
      float2v h0v1 = gnewv[1] + len0v;
      float2v mmv0 = v2max(L19v[0], h0v0);
      float2v mmv1 = v2max(L19v[1], h0v1);
      float2v eLv0 = v2exp2(L19v[0] - mmv0);
      float2v eLv1 = v2exp2(L19v[1] - mmv1);
      float2v ehv0 = v2exp2(h0v0 - mmv0);
      float2v ehv1 = v2exp2(h0v1 - mmv1);
      float2v sfv0 = eLv0 + ehv0;
      float2v sfv1 = eLv1 + ehv1;
      float2v mab0 = mmv0 + cumv[0];
      float2v mab1 = mmv1 + cumv[1];
      float wm0 = wave_max64(fmaxf(mab0.x, mab0.y));
      float wm1 = wave_max64(fmaxf(mab1.x, mab1.y));
      float p00 = sfv0.x * __builtin_amdgcn_exp2f(mab0.x - wm0);
      float p01 = sfv0.y * __builtin_amdgcn_exp2f(mab0.y - wm0);
      float p10 = sfv1.x * __builtin_amdgcn_exp2f(mab1.x - wm1);
      float p11 = sfv1.y * __builtin_amdgcn_exp2f(mab1.y - wm1);
      int pk0 = __builtin_amdgcn_cvt_pk_fp8_f32(p00, p01, 0, false);
      int pk1 = __builtin_amdgcn_cvt_pk_fp8_f32(p10, p11, 0, false);
      s_p[0][lane] = (unsigned short)pk0;
      s_p[1][lane] = (unsigned short)pk1;
      if (t == lenP[0]) {
        float psum = wave_sum64(p00 + p01);
        if (lane == 0) out[bA] = LN2 * (wm0 + __builtin_amdgcn_logf(psum));
      }
      if (t == lenP[1]) {
        float psum = wave_sum64(p10 + p11);
        if (lane == 0) out[bB] = LN2 * (wm1 + __builtin_amdgcn_logf(psum));
      }

      // ---- A-frags: both reads after both writes (one wait covers) ----
      const int4* ap0 = (const int4*)((const char*)s_p[0] + lg4 * 32);
      const int4* ap1 = (const int4*)((const char*)s_p[1] + lg4 * 32);
      int4 ra0 = ap0[0], rb0 = ap0[1];
      int4 ra1 = ap1[0], rb1 = ap1[1];
      int8v A0, A1;
      A0[0] = ra0.x; A0[1] = ra0.y; A0[2] = ra0.z; A0[3] = ra0.w;
      A0[4] = rb0.x; A0[5] = rb0.y; A0[6] = rb0.z; A0[7] = rb0.w;
      A1[0] = ra1.x; A1[1] = ra1.y; A1[2] = ra1.z; A1[3] = ra1.w;
      A1[4] = rb1.x; A1[5] = rb1.y; A1[6] = rb1.z; A1[7] = rb1.w;

      // ---- shadow window, both batches, packed channels ----
      float2v phi0 = v2exp2(v2minc(aav[0] - mmv0, 100.0f));
      float2v phi1 = v2exp2(v2minc(aav[1] - mmv1, 100.0f));
      #pragma unroll
      for (int j = Kk - 2; j >= 1; j--) {
        wvv[0][j] = wvv[0][j - 1] * (E2v[j] * phi0);
        wvv[1][j] = wvv[1][j - 1] * (E2v[j] * phi1);
      }
      wvv[0][0] = ehv0 * E2v[0];
      wvv[1][0] = ehv1 * E2v[0];
      float2v S0, S1;
      {
        float2v a0 = (wvv[0][0] + wvv[0][1]) + (wvv[0][2] + wvv[0][3]);
        float2v a1 = (wvv[0][4] + wvv[0][5]) + (wvv[0][6] + wvv[0][7]);
        float2v a2 = (wvv[0][8] + wvv[0][9]) + (wvv[0][10] + wvv[0][11]);
        float2v a3 = (wvv[0][12] + wvv[0][13]) + (wvv[0][14] + wvv[0][15]);
        float2v a4 = (wvv[0][16] + wvv[0][17]) + wvv[0][18];
        S0 = ((a0 + a1) + (a2 + a3)) + a4;
        float2v b0 = (wvv[1][0] + wvv[1][1]) + (wvv[1][2] + wvv[1][3]);
        float2v b1 = (wvv[1][4] + wvv[1][5]) + (wvv[1][6] + wvv[1][7]);
        float2v b2 = (wvv[1][8] + wvv[1][9]) + (wvv[1][10] + wvv[1][11]);
        float2v b3 = (wvv[1][12] + wvv[1][13]) + (wvv[1][14] + wvv[1][15]);
        float2v b4 = (wvv[1][16] + wvv[1][17]) + wvv[1][18];
        S1 = ((b0 + b1) + (b2 + b3)) + b4;
      }

      // ---- matvec: 16 independent MFMAs, both batches ----
      float4v D0, D1, D2, D3, D4, D5, D6, D7;
      float4v F0, F1, F2, F3, F4, F5, F6, F7;
      {
        float4v z = {0.0f, 0.0f, 0.0f, 0.0f};
        D0 = __builtin_amdgcn_mfma_scale_f32_16x16x128_f8f6f4(A0, Tf[0], z, 0, 0, 0, sc1, 0, sc1);
        F0 = __builtin_amdgcn_mfma_scale_f32_16x16x128_f8f6f4(A1, Tf[0], z, 0, 0, 0, sc1, 0, sc1);
        D1 = __builtin_amdgcn_mfma_scale_f32_16x16x128_f8f6f4(A0, Tf[1], z, 0, 0, 0, sc1, 0, sc1);
        F1 = __builtin_amdgcn_mfma_scale_f32_16x16x128_f8f6f4(A1, Tf[1], z, 0, 0, 0, sc1, 0, sc1);
        D2 = __builtin_amdgcn_mfma_scale_f32_16x16x128_f8f6f4(A0, Tf[2], z, 0, 0, 0, sc1, 0, sc1);
        F2 = __builtin_amdgcn_mfma_scale_f32_16x16x128_f8f6f4(A1, Tf[2], z, 0, 0, 0, sc1, 0, sc1);
        D3 = __builtin_amdgcn_mfma_scale_f32_16x16x128_f8f6f4(A0, Tf[3], z, 0, 0, 0, sc1, 0, sc1);
        F3 = __builtin_amdgcn_mfma_scale_f32_16x16x128_f8f6f4(A1, Tf[3], z, 0, 0, 0, sc1, 0, sc1);
        D4 = __builtin_amdgcn_mfma_scale_f32_16x16x128_f8f6f4(A0, Tf[4], z, 0, 0, 0, sc1, 0, sc1);
        F4 = __builtin_amdgcn_mfma_scale_f32_16x16x128_f8f6f4(A1, Tf[4], z, 0, 0, 0, sc1, 0, sc1);
        D5 = __builtin_amdgcn_mfma_scale_f32_16x16x128_f8f6f4(A0, Tf[5], z, 0, 0, 0, sc1, 0, sc1);
        F5 = __builtin_amdgcn_mfma_scale_f32_16x16x128_f8f6f4(A1, Tf[5], z, 0, 0, 0, sc1, 0, sc1);
        D6 = __builtin_amdgcn_mfma_scale_f32_16x16x128_f8f6f4(A0, Tf[6], z, 0, 0, 0, sc1, 0, sc1);
        F6 = __builtin_amdgcn_mfma_scale_f32_16x16x128_f8f6f4(A1, Tf[6], z, 0, 0, 0, sc1, 0, sc1);
        D7 = __builtin_amdgcn_mfma_scale_f32_16x16x128_f8f6f4(A0, Tf[7], z, 0, 0, 0, sc1, 0, sc1);
        F7 = __builtin_amdgcn_mfma_scale_f32_16x16x128_f8f6f4(A1, Tf[7], z, 0, 0, 0, sc1, 0, sc1);
      }

      // ---- extract q, close recurrences (both batches) ----
      float q00 = (lg4 == 0) ? D0[0] : (lg4 == 1) ? D1[0] : (lg4 == 2) ? D2[0] : D3[0];
      float q01 = (lg4 == 0) ? D4[0] : (lg4 == 1) ? D5[0] : (lg4 == 2) ? D6[0] : D7[0];
      float q10 = (lg4 == 0) ? F0[0] : (lg4 == 1) ? F1[0] : (lg4 == 2) ? F2[0] : F3[0];
      float q11 = (lg4 == 0) ? F4[0] : (lg4 == 1) ? F5[0] : (lg4 == 2) ? F6[0] : F7[0];
      float rel00 = cumv[0].x - wm0, rel01 = cumv[0].y - wm0;
      float rel10 = cumv[1].x - wm1, rel11 = cumv[1].y - wm1;
      gnewv[0].x = (q00 > 0.0f) ? (__builtin_amdgcn_logf(q00) - 6.0f - rel00) : BIG_NEG;
      gnewv[0].y = (q01 > 0.0f) ? (__builtin_amdgcn_logf(q01) - 6.0f - rel01) : BIG_NEG;
      gnewv[1].x = (q10 > 0.0f) ? (__builtin_amdgcn_logf(q10) - 6.0f - rel10) : BIG_NEG;
      gnewv[1].y = (q11 > 0.0f) ? (__builtin_amdgcn_logf(q11) - 6.0f - rel11) : BIG_NEG;

      aav[0] = mmv0;  L19v[0] = mmv0 + v2log2(S0);  cumv[0] += ev[0][i];
      aav[1] = mmv1;  L19v[1] = mmv1 + v2log2(S1);  cumv[1] += ev[1][i];

      if (t == tmax) { done = true; break; }
    }
    if (!done) {
      #pragma unroll
      for (int i = 0; i < 8; i++) { ev[0][i] = env[0][i]; ev[1][i] = env[1][i]; }
    }
  }
}

extern "C" void kernel_launch(void* const* d_in, const int* in_sizes, int n_in,
                              void* d_out, int out_size, void* d_ws, size_t ws_size,
                              hipStream_t stream) {
  const float* features = (const float*)d_in[0];
  const int* lengths = (const int*)d_in[1];
  const float* means = (const float*)d_in[2];
  const float* cov = (const float*)d_in[3];
  const float* tl = (const float*)d_in[4];
  const float* il = (const float*)d_in[5];
  const float* plr = (const float*)d_in[6];
  float* out = (float*)d_out;
  float* ws = (float*)d_ws;

  prep_kernel<<<1, 256, 0, stream>>>(means, cov, tl, il, plr, ws);
  xq_kernel<<<(Bb * Nn) / 4, 256, 0, stream>>>(features, ws);
  emis_mfma_kernel<<<Bb * (Nn / 32), 256, 0, stream>>>(features, ws);
  scan_kernel<<<8, 64, 0, stream>>>(lengths, ws, out);
}